// Round 20
// baseline (1275.505 us; speedup 1.0000x reference)
//
#include <hip/hip_runtime.h>

typedef _Float16 f16;
typedef _Float16 f16x4_t __attribute__((ext_vector_type(4)));
typedef _Float16 f16x8_t __attribute__((ext_vector_type(8)));
typedef float    f32x4_t __attribute__((ext_vector_type(4)));

#define HD 512          // h
#define CD 256          // c
#define ND 512          // N (codebook)
#define MROWS (4*24*2048)
#define BM 64
#define NTHR 512
#define NWG 512         // persistent: 2 WGs/CU x 256 CUs
#define NTILE (MROWS / BM / NWG)   // 6 tiles per WG
#define TINV 10.0f      // 1/TEMP

// Fragment layout for MFMA B operands (validated R6): element (n,h) ->
// ((((n>>4)*16+(h>>5))*4+((h>>3)&3))*16+(n&15))*8+(h&7)
__device__ __forceinline__ int fragoff(int n, int h) {
  return ((((n >> 4) * 16 + (h >> 5)) * 4 + ((h >> 3) & 3)) * 16 + (n & 15)) * 8 + (h & 7);
}

// ---------------- prep: M = Wp @ Wq -> fp16 fragments; sb[n] = dot(Wp[n], bq)
__global__ void prep_M(const float* __restrict__ Wp, const float* __restrict__ Wq,
                       const float* __restrict__ bq, f16* __restrict__ MtF,
                       float* __restrict__ sb) {
  const int n = blockIdx.x;   // 0..511
  const int t = threadIdx.x;  // 0..255
  __shared__ float wpr[CD];
  __shared__ float sred[CD];
  wpr[t] = Wp[n * CD + t];
  __syncthreads();
  float a0 = 0.f, a1 = 0.f;
  #pragma unroll 8
  for (int c = 0; c < CD; ++c) {
    const float w = wpr[c];
    a0 = fmaf(w, Wq[c * HD + t], a0);
    a1 = fmaf(w, Wq[c * HD + t + 256], a1);
  }
  MtF[fragoff(n, t)]       = (f16)a0;
  MtF[fragoff(n, t + 256)] = (f16)a1;
  sred[t] = wpr[t] * bq[t];
  __syncthreads();
  for (int s = 128; s > 0; s >>= 1) {
    if (t < s) sred[t] += sred[t + s];
    __syncthreads();
  }
  if (t == 0) sb[n] = sred[0];
}

// ---------------- prep: WpF = GEMM3 B fragments (k-dim = n, cols = c), validated R6
__global__ void prep_WpF(const float* __restrict__ Wp, f16* __restrict__ WpF) {
  const int bx   = blockIdx.x;        // cf*16 + ks, 0..255
  const int lane = threadIdx.x;       // 0..63
  const int cf = bx >> 4, ks = bx & 15;
  const int q4 = lane >> 4, l16 = lane & 15;
  f16x8_t v;
  #pragma unroll
  for (int j = 0; j < 8; ++j)
    v[j] = (f16)Wp[(ks * 32 + q4 * 8 + j) * CD + cf * 16 + l16];
  *(f16x8_t*)(WpF + ((bx * 64) + lane) * 8) = v;
}

// ---------------- persistent fused main = R19 tile body x 6 tiles per WG.
// R14 retry with the thrash poison removed: R14's persistence desynced WGs and
// the ALLOCATING H/Q/P streams evicted B-fragments from L2 (FETCH 406MB->2.07GB).
// R19 proved NT loads/stores keep FETCH clean at 405MB. Persistent + NT should
// give desync phase-overlap (stage of one WG under GEMM of another) with B hot.
// FETCH is the falsifier: >=600MB means NT doesn't protect B -> abandon.
// s_setprio around MFMA (T5's desync regime). Merged reduce (3 barriers + trail).
// Register model: (512,4) -> 128 total regs/wave = 64 arch VGPR + 64 AGPR acc.
// SWIZZLE RULE (R4): XOR the FULL byte offset (XOR-last); mask (row&31)<<4 (R17).
__global__ __launch_bounds__(NTHR, 4)
void fused_main(const float* __restrict__ Hl, const f16* __restrict__ MtF,
                const f16* __restrict__ WpF, const float* __restrict__ sb,
                float* __restrict__ outP, float* __restrict__ outQ) {
  __shared__ __align__(16) char AQraw[BM * HD * 2];   // 64 KiB: H fp16 -> Q fp16
  __shared__ __align__(16) float red[BM][8];

  const int tid  = threadIdx.x;
  const int lane = tid & 63;
  const int wid  = tid >> 6;         // 0..7
  const int q4   = lane >> 4;        // 0..3
  const int l16  = lane & 15;

  float sb10[4];
  #pragma unroll
  for (int nf = 0; nf < 4; ++nf) sb10[nf] = sb[wid * 64 + nf * 16 + l16] * TINV;

  for (int t = 0; t < NTILE; ++t) {
    const long rowbase = (long)(t * NWG + blockIdx.x) * BM;

    // ---- stage H: 64 rows x 512 fp32 -> fp16 LDS (swizzled); NT loads ----
    {
      const f32x4_t* __restrict__ src = (const f32x4_t*)(Hl + rowbase * HD);
      #pragma unroll
      for (int it = 0; it < (BM * HD / 4) / NTHR; ++it) {   // 16 iters
        const int f = it * NTHR + tid;
        const f32x4_t v = __builtin_nontemporal_load(&src[f]);
        const int row = f >> 7;
        int byteoff = row * (HD * 2) + ((f & 127) << 3);
        byteoff ^= (row & 31) << 4;                  // XOR-last!
        f16x4_t h;
        h[0] = (f16)v[0]; h[1] = (f16)v[1]; h[2] = (f16)v[2]; h[3] = (f16)v[3];
        *(f16x4_t*)(AQraw + byteoff) = h;
      }
    }
    __syncthreads();                                 // barrier 1

    // ---- GEMM1: wave tile 64 rows x 64 cols; B from MtF (L2) ----
    f32x4_t acc[4][4];
    #pragma unroll
    for (int i = 0; i < 4; ++i)
      #pragma unroll
      for (int j = 0; j < 4; ++j)
        #pragma unroll
        for (int k = 0; k < 4; ++k) acc[i][j][k] = 0.f;

    {
      const char* __restrict__ mb = (const char*)MtF + (wid * 4 * 16) * 1024 + lane * 16;
      __builtin_amdgcn_s_setprio(1);
      for (int ks = 0; ks < 16; ++ks) {
        f16x8_t a[4];
        #pragma unroll
        for (int mf = 0; mf < 4; ++mf) {
          const int arow = mf * 16 + l16;
          int byteoff = arow * (HD * 2) + ks * 64 + q4 * 16;
          byteoff ^= (arow & 31) << 4;               // XOR-last!
          a[mf] = *(const f16x8_t*)(AQraw + byteoff);
        }
        #pragma unroll
        for (int nf = 0; nf < 4; ++nf) {
          const f16x8_t b = *(const f16x8_t*)(mb + (nf * 16 + ks) * 1024);
          #pragma unroll
          for (int mf = 0; mf < 4; ++mf)
            acc[mf][nf] = __builtin_amdgcn_mfma_f32_16x16x32_f16(a[mf], b, acc[mf][nf], 0, 0, 0);
        }
      }
      __builtin_amdgcn_s_setprio(0);
    }

    // ---- softmax over N=512, direct exp (|logit| <~ 54 << 88) ----
    float ps[4][4];
    #pragma unroll
    for (int mf = 0; mf < 4; ++mf)
      #pragma unroll
      for (int r = 0; r < 4; ++r) ps[mf][r] = 0.f;
    #pragma unroll
    for (int mf = 0; mf < 4; ++mf)
      #pragma unroll
      for (int nf = 0; nf < 4; ++nf)
        #pragma unroll
        for (int r = 0; r < 4; ++r) {
          const float e = __expf(fmaf(acc[mf][nf][r], TINV, sb10[nf]));
          acc[mf][nf][r] = e;
          ps[mf][r] += e;
        }
    #pragma unroll
    for (int st = 8; st >= 1; st >>= 1)
      #pragma unroll
      for (int mf = 0; mf < 4; ++mf)
        #pragma unroll
        for (int r = 0; r < 4; ++r)
          ps[mf][r] += __shfl_xor(ps[mf][r], st, 64);

    if (l16 == 0) {
      #pragma unroll
      for (int mf = 0; mf < 4; ++mf)
        #pragma unroll
        for (int r = 0; r < 4; ++r)
          red[mf * 16 + q4 * 4 + r][wid] = ps[mf][r];
    }
    __syncthreads();                                 // barrier 2 (merged reduce)

    // ---- normalize: Q fp32 NT stores + Q fp16 into LDS (transpose) ----
    #pragma unroll
    for (int mf = 0; mf < 4; ++mf) {
      float rinv[4];
      #pragma unroll
      for (int r = 0; r < 4; ++r) {
        const f32x4_t* rr = (const f32x4_t*)red[mf * 16 + q4 * 4 + r];
        const f32x4_t s0 = rr[0], s1 = rr[1];
        rinv[r] = 1.0f / (s0[0] + s0[1] + s0[2] + s0[3] + s1[0] + s1[1] + s1[2] + s1[3]);
      }
      #pragma unroll
      for (int nf = 0; nf < 4; ++nf)
        #pragma unroll
        for (int r = 0; r < 4; ++r) {
          const int rloc = mf * 16 + q4 * 4 + r;
          const int col  = wid * 64 + nf * 16 + l16;
          const float q = acc[mf][nf][r] * rinv[r];
          __builtin_nontemporal_store(q, &outQ[(rowbase + rloc) * ND + col]);
          int byteoff = rloc * (ND * 2) + col * 2;
          byteoff ^= (rloc & 31) << 4;               // XOR-last!
          *(f16*)(AQraw + byteoff) = (f16)q;
        }
    }
    __syncthreads();                                 // barrier 3: Q-LDS ready

    // ---- GEMM3: wave tile 64 rows x 32 cols; A from LDS, B from WpF (L2) ----
    f32x4_t acc2[4][2];
    #pragma unroll
    for (int i = 0; i < 4; ++i)
      #pragma unroll
      for (int j = 0; j < 2; ++j)
        #pragma unroll
        for (int k = 0; k < 4; ++k) acc2[i][j][k] = 0.f;

    {
      const char* __restrict__ wb = (const char*)WpF + (wid * 2 * 16) * 1024 + lane * 16;
      __builtin_amdgcn_s_setprio(1);
      for (int ks = 0; ks < 16; ++ks) {
        f16x8_t a[4];
        #pragma unroll
        for (int mf = 0; mf < 4; ++mf) {
          const int arow = mf * 16 + l16;
          int byteoff = arow * (ND * 2) + ks * 64 + q4 * 16;
          byteoff ^= (arow & 31) << 4;               // XOR-last!
          a[mf] = *(const f16x8_t*)(AQraw + byteoff);
        }
        #pragma unroll
        for (int nf = 0; nf < 2; ++nf) {
          const f16x8_t b = *(const f16x8_t*)(wb + (nf * 16 + ks) * 1024);
          #pragma unroll
          for (int mf = 0; mf < 4; ++mf)
            acc2[mf][nf] = __builtin_amdgcn_mfma_f32_16x16x32_f16(a[mf], b, acc2[mf][nf], 0, 0, 0);
        }
      }
      __builtin_amdgcn_s_setprio(0);
    }

    // ---- P fp32 NT stores from regs ----
    #pragma unroll
    for (int mf = 0; mf < 4; ++mf)
      #pragma unroll
      for (int nf = 0; nf < 2; ++nf)
        #pragma unroll
        for (int r = 0; r < 4; ++r) {
          const long row = rowbase + mf * 16 + q4 * 4 + r;
          const int  col = wid * 32 + nf * 16 + l16;
          __builtin_nontemporal_store(acc2[mf][nf][r], &outP[row * CD + col]);
        }
    __syncthreads();                                 // trail: protect AQraw for next stage
  }
}

extern "C" void kernel_launch(void* const* d_in, const int* in_sizes, int n_in,
                              void* d_out, int out_size, void* d_ws, size_t ws_size,
                              hipStream_t stream) {
  const float* Hl = (const float*)d_in[0];   // (B,T,V,H)
  const float* Wp = (const float*)d_in[1];   // (N,C)
  const float* Wq = (const float*)d_in[2];   // (C,H)
  const float* bq = (const float*)d_in[3];   // (C,)

  float* outP = (float*)d_out;                         // (M, C)
  float* outQ = (float*)d_out + (long)MROWS * CD;      // (M, N)

  f16*   MtF = (f16*)d_ws;                                        // 512 KiB
  f16*   WpF = (f16*)((char*)d_ws + ND * HD * 2);                 // 256 KiB
  float* sb  = (float*)((char*)d_ws + ND * HD * 2 + CD * ND * 2); // 2 KiB

  prep_M  <<<ND, CD, 0, stream>>>(Wp, Wq, bq, MtF, sb);
  prep_WpF<<<CD, 64, 0, stream>>>(Wp, WpF);
  fused_main<<<NWG, NTHR, 0, stream>>>(Hl, MtF, WpF, sb, outP, outQ);
}

// Round 21
// 464.065 us; speedup vs baseline: 2.7485x; 2.7485x over previous
//
#include <hip/hip_runtime.h>

typedef _Float16 f16;
typedef _Float16 f16x4_t __attribute__((ext_vector_type(4)));
typedef _Float16 f16x8_t __attribute__((ext_vector_type(8)));
typedef float    f32x4_t __attribute__((ext_vector_type(4)));

#define HD 512          // h
#define CD 256          // c
#define ND 512          // N (codebook)
#define MROWS (4*24*2048)
#define BM 64
#define NTHR 512
#define TINV 10.0f      // 1/TEMP

// Fragment layout for MFMA B operands (validated R6): element (n,h) ->
// ((((n>>4)*16+(h>>5))*4+((h>>3)&3))*16+(n&15))*8+(h&7)
__device__ __forceinline__ int fragoff(int n, int h) {
  return ((((n >> 4) * 16 + (h >> 5)) * 4 + ((h >> 3) & 3)) * 16 + (n & 15)) * 8 + (h & 7);
}

// ---------------- prep: M = Wp @ Wq -> fp16 fragments; sb[n] = dot(Wp[n], bq)
__global__ void prep_M(const float* __restrict__ Wp, const float* __restrict__ Wq,
                       const float* __restrict__ bq, f16* __restrict__ MtF,
                       float* __restrict__ sb) {
  const int n = blockIdx.x;   // 0..511
  const int t = threadIdx.x;  // 0..255
  __shared__ float wpr[CD];
  __shared__ float sred[CD];
  wpr[t] = Wp[n * CD + t];
  __syncthreads();
  float a0 = 0.f, a1 = 0.f;
  #pragma unroll 8
  for (int c = 0; c < CD; ++c) {
    const float w = wpr[c];
    a0 = fmaf(w, Wq[c * HD + t], a0);
    a1 = fmaf(w, Wq[c * HD + t + 256], a1);
  }
  MtF[fragoff(n, t)]       = (f16)a0;
  MtF[fragoff(n, t + 256)] = (f16)a1;
  sred[t] = wpr[t] * bq[t];
  __syncthreads();
  for (int s = 128; s > 0; s >>= 1) {
    if (t < s) sred[t] += sred[t + s];
    __syncthreads();
  }
  if (t == 0) sb[n] = sred[0];
}

// ---------------- prep: WpF = GEMM3 B fragments (k-dim = n, cols = c), validated R6
__global__ void prep_WpF(const float* __restrict__ Wp, f16* __restrict__ WpF) {
  const int bx   = blockIdx.x;        // cf*16 + ks, 0..255
  const int lane = threadIdx.x;       // 0..63
  const int cf = bx >> 4, ks = bx & 15;
  const int q4 = lane >> 4, l16 = lane & 15;
  f16x8_t v;
  #pragma unroll
  for (int j = 0; j < 8; ++j)
    v[j] = (f16)Wp[(ks * 32 + q4 * 8 + j) * CD + cf * 16 + l16];
  *(f16x8_t*)(WpF + ((bx * 64) + lane) * 8) = v;
}

// ---------------- fused main: R19 champion + 1 diff (R21):
// Q global store is now COALESCED-NT from LDS (1KB/instr contiguous = full-line
// DRAM granule) instead of scattered per-element NT (64B segments -> ~2x write
// amplification at 128B granule: R19 WRITE 1.14GB vs 603 ideal). Placed after
// barrier 4 (Q-LDS ready), before GEMM3 -- no extra barrier, stores drain under
// GEMM3+P. Q output becomes fp16-rounded (R6/R12 precedent, absmax 3.9e-3 ok).
// P stays direct-NT to isolate the variable.
// Register model: (512,4) -> 128 total regs/wave = 64 arch VGPR + 64 AGPR acc.
// SWIZZLE RULE (R4): XOR the FULL byte offset (XOR-last); mask (row&31)<<4 (R17).
__global__ __launch_bounds__(NTHR, 4)
void fused_main(const float* __restrict__ Hl, const f16* __restrict__ MtF,
                const f16* __restrict__ WpF, const float* __restrict__ sb,
                float* __restrict__ outP, float* __restrict__ outQ) {
  __shared__ __align__(16) char AQraw[BM * HD * 2];   // 64 KiB: H fp16 -> Q fp16
  __shared__ float red[BM][8];
  __shared__ float rstat[BM];

  const int tid  = threadIdx.x;
  const int lane = tid & 63;
  const int wid  = tid >> 6;         // 0..7
  const int q4   = lane >> 4;        // 0..3
  const int l16  = lane & 15;
  const long rowbase = (long)blockIdx.x * BM;

  // ---- stage H: 64 rows x 512 fp32 -> fp16 LDS (swizzled); NT loads ----
  {
    const f32x4_t* __restrict__ src = (const f32x4_t*)(Hl + rowbase * HD);
    #pragma unroll
    for (int it = 0; it < (BM * HD / 4) / NTHR; ++it) {   // 16 iters
      const int f = it * NTHR + tid;
      const f32x4_t v = __builtin_nontemporal_load(&src[f]);
      const int row = f >> 7;
      int byteoff = row * (HD * 2) + ((f & 127) << 3);
      byteoff ^= (row & 31) << 4;                    // XOR-last!
      f16x4_t h;
      h[0] = (f16)v[0]; h[1] = (f16)v[1]; h[2] = (f16)v[2]; h[3] = (f16)v[3];
      *(f16x4_t*)(AQraw + byteoff) = h;
    }
  }
  __syncthreads();                                   // barrier 1

  // ---- GEMM1: wave tile 64 rows x 64 cols; B from MtF (L2) ----
  f32x4_t acc[4][4];
  #pragma unroll
  for (int i = 0; i < 4; ++i)
    #pragma unroll
    for (int j = 0; j < 4; ++j)
      #pragma unroll
      for (int k = 0; k < 4; ++k) acc[i][j][k] = 0.f;

  {
    const char* __restrict__ mb = (const char*)MtF + (wid * 4 * 16) * 1024 + lane * 16;
    for (int ks = 0; ks < 16; ++ks) {
      f16x8_t a[4];
      #pragma unroll
      for (int mf = 0; mf < 4; ++mf) {
        const int arow = mf * 16 + l16;
        int byteoff = arow * (HD * 2) + ks * 64 + q4 * 16;
        byteoff ^= (arow & 31) << 4;                 // XOR-last!
        a[mf] = *(const f16x8_t*)(AQraw + byteoff);
      }
      #pragma unroll
      for (int nf = 0; nf < 4; ++nf) {
        const f16x8_t b = *(const f16x8_t*)(mb + (nf * 16 + ks) * 1024);
        #pragma unroll
        for (int mf = 0; mf < 4; ++mf)
          acc[mf][nf] = __builtin_amdgcn_mfma_f32_16x16x32_f16(a[mf], b, acc[mf][nf], 0, 0, 0);
      }
    }
  }

  // ---- softmax over N=512, direct exp (|logit| <~ 54 << 88) ----
  // thread rows: mf*16 + q4*4 + r; cols: wid*64 + nf*16 + l16
  float sb10[4];
  #pragma unroll
  for (int nf = 0; nf < 4; ++nf) sb10[nf] = sb[wid * 64 + nf * 16 + l16] * TINV;

  float ps[4][4];
  #pragma unroll
  for (int mf = 0; mf < 4; ++mf)
    #pragma unroll
    for (int r = 0; r < 4; ++r) ps[mf][r] = 0.f;
  #pragma unroll
  for (int mf = 0; mf < 4; ++mf)
    #pragma unroll
    for (int nf = 0; nf < 4; ++nf)
      #pragma unroll
      for (int r = 0; r < 4; ++r) {
        const float e = __expf(fmaf(acc[mf][nf][r], TINV, sb10[nf]));
        acc[mf][nf][r] = e;
        ps[mf][r] += e;
      }
  #pragma unroll
  for (int st = 8; st >= 1; st >>= 1)
    #pragma unroll
    for (int mf = 0; mf < 4; ++mf)
      #pragma unroll
      for (int r = 0; r < 4; ++r)
        ps[mf][r] += __shfl_xor(ps[mf][r], st, 64);

  if (l16 == 0) {
    #pragma unroll
    for (int mf = 0; mf < 4; ++mf)
      #pragma unroll
      for (int r = 0; r < 4; ++r)
        red[mf * 16 + q4 * 4 + r][wid] = ps[mf][r];
  }
  __syncthreads();                                   // barrier 2
  if (tid < BM) {
    const float* rr = red[tid];
    rstat[tid] = 1.0f / (rr[0] + rr[1] + rr[2] + rr[3] + rr[4] + rr[5] + rr[6] + rr[7]);
  }
  __syncthreads();                                   // barrier 3

  // ---- normalize: Q fp16 into LDS only (global store happens coalesced later) ----
  #pragma unroll
  for (int mf = 0; mf < 4; ++mf) {
    float rinv[4];
    #pragma unroll
    for (int r = 0; r < 4; ++r)
      rinv[r] = rstat[mf * 16 + q4 * 4 + r];
    #pragma unroll
    for (int nf = 0; nf < 4; ++nf)
      #pragma unroll
      for (int r = 0; r < 4; ++r) {
        const int rloc = mf * 16 + q4 * 4 + r;
        const int col  = wid * 64 + nf * 16 + l16;
        int byteoff = rloc * (ND * 2) + col * 2;
        byteoff ^= (rloc & 31) << 4;                 // XOR-last!
        *(f16*)(AQraw + byteoff) = (f16)(acc[mf][nf][r] * rinv[r]);
      }
  }
  __syncthreads();                                   // barrier 4: Q-LDS ready

  // ---- Q global store: COALESCED NT float4 from LDS (1KB/instr, full lines) ----
  {
    #pragma unroll
    for (int it = 0; it < (BM * ND / 4) / NTHR; ++it) {   // 16 iters
      const int f = it * NTHR + tid;
      const int row = f >> 7;
      int byteoff = row * (ND * 2) + ((f & 127) << 3);
      byteoff ^= (row & 31) << 4;                    // XOR-last!
      const f16x4_t qv = *(const f16x4_t*)(AQraw + byteoff);
      f32x4_t o;
      o[0] = (float)qv[0]; o[1] = (float)qv[1]; o[2] = (float)qv[2]; o[3] = (float)qv[3];
      __builtin_nontemporal_store(
          o, (f32x4_t*)(outQ + (rowbase + row) * ND + ((f & 127) << 2)));
    }
  }

  // ---- GEMM3: wave tile 64 rows x 32 cols; A from LDS, B from WpF (L2) ----
  f32x4_t acc2[4][2];
  #pragma unroll
  for (int i = 0; i < 4; ++i)
    #pragma unroll
    for (int j = 0; j < 2; ++j)
      #pragma unroll
      for (int k = 0; k < 4; ++k) acc2[i][j][k] = 0.f;

  {
    const char* __restrict__ wb = (const char*)WpF + (wid * 2 * 16) * 1024 + lane * 16;
    for (int ks = 0; ks < 16; ++ks) {
      f16x8_t a[4];
      #pragma unroll
      for (int mf = 0; mf < 4; ++mf) {
        const int arow = mf * 16 + l16;
        int byteoff = arow * (ND * 2) + ks * 64 + q4 * 16;
        byteoff ^= (arow & 31) << 4;                 // XOR-last!
        a[mf] = *(const f16x8_t*)(AQraw + byteoff);
      }
      #pragma unroll
      for (int nf = 0; nf < 2; ++nf) {
        const f16x8_t b = *(const f16x8_t*)(wb + (nf * 16 + ks) * 1024);
        #pragma unroll
        for (int mf = 0; mf < 4; ++mf)
          acc2[mf][nf] = __builtin_amdgcn_mfma_f32_16x16x32_f16(a[mf], b, acc2[mf][nf], 0, 0, 0);
      }
    }
  }

  // ---- P fp32 NT stores from regs (scattered; isolates the Q variable) ----
  #pragma unroll
  for (int mf = 0; mf < 4; ++mf)
    #pragma unroll
    for (int nf = 0; nf < 2; ++nf)
      #pragma unroll
      for (int r = 0; r < 4; ++r) {
        const long row = rowbase + mf * 16 + q4 * 4 + r;
        const int  col = wid * 32 + nf * 16 + l16;
        __builtin_nontemporal_store(acc2[mf][nf][r], &outP[row * CD + col]);
      }
}

extern "C" void kernel_launch(void* const* d_in, const int* in_sizes, int n_in,
                              void* d_out, int out_size, void* d_ws, size_t ws_size,
                              hipStream_t stream) {
  const float* Hl = (const float*)d_in[0];   // (B,T,V,H)
  const float* Wp = (const float*)d_in[1];   // (N,C)
  const float* Wq = (const float*)d_in[2];   // (C,H)
  const float* bq = (const float*)d_in[3];   // (C,)

  float* outP = (float*)d_out;                         // (M, C)
  float* outQ = (float*)d_out + (long)MROWS * CD;      // (M, N)

  f16*   MtF = (f16*)d_ws;                                        // 512 KiB
  f16*   WpF = (f16*)((char*)d_ws + ND * HD * 2);                 // 256 KiB
  float* sb  = (float*)((char*)d_ws + ND * HD * 2 + CD * ND * 2); // 2 KiB

  prep_M  <<<ND, CD, 0, stream>>>(Wp, Wq, bq, MtF, sb);
  prep_WpF<<<CD, 64, 0, stream>>>(Wp, WpF);
  fused_main<<<MROWS / BM, NTHR, 0, stream>>>(Hl, MtF, WpF, sb, outP, outQ);
}

// Round 22
// 428.775 us; speedup vs baseline: 2.9748x; 1.0823x over previous
//
#include <hip/hip_runtime.h>

typedef _Float16 f16;
typedef _Float16 f16x4_t __attribute__((ext_vector_type(4)));
typedef _Float16 f16x8_t __attribute__((ext_vector_type(8)));
typedef float    f32x4_t __attribute__((ext_vector_type(4)));

#define HD 512          // h
#define CD 256          // c
#define ND 512          // N (codebook)
#define MROWS (4*24*2048)
#define BM 64
#define NTHR 512
#define TINV 10.0f      // 1/TEMP

// Fragment layout for MFMA B operands (validated R6): element (n,h) ->
// ((((n>>4)*16+(h>>5))*4+((h>>3)&3))*16+(n&15))*8+(h&7)
__device__ __forceinline__ int fragoff(int n, int h) {
  return ((((n >> 4) * 16 + (h >> 5)) * 4 + ((h >> 3) & 3)) * 16 + (n & 15)) * 8 + (h & 7);
}

// ---------------- prep: M = Wp @ Wq -> fp16 fragments; sb[n] = dot(Wp[n], bq)
__global__ void prep_M(const float* __restrict__ Wp, const float* __restrict__ Wq,
                       const float* __restrict__ bq, f16* __restrict__ MtF,
                       float* __restrict__ sb) {
  const int n = blockIdx.x;   // 0..511
  const int t = threadIdx.x;  // 0..255
  __shared__ float wpr[CD];
  __shared__ float sred[CD];
  wpr[t] = Wp[n * CD + t];
  __syncthreads();
  float a0 = 0.f, a1 = 0.f;
  #pragma unroll 8
  for (int c = 0; c < CD; ++c) {
    const float w = wpr[c];
    a0 = fmaf(w, Wq[c * HD + t], a0);
    a1 = fmaf(w, Wq[c * HD + t + 256], a1);
  }
  MtF[fragoff(n, t)]       = (f16)a0;
  MtF[fragoff(n, t + 256)] = (f16)a1;
  sred[t] = wpr[t] * bq[t];
  __syncthreads();
  for (int s = 128; s > 0; s >>= 1) {
    if (t < s) sred[t] += sred[t + s];
    __syncthreads();
  }
  if (t == 0) sb[n] = sred[0];
}

// ---------------- prep: WpF = GEMM3 B fragments (k-dim = n, cols = c), validated R6
__global__ void prep_WpF(const float* __restrict__ Wp, f16* __restrict__ WpF) {
  const int bx   = blockIdx.x;        // cf*16 + ks, 0..255
  const int lane = threadIdx.x;       // 0..63
  const int cf = bx >> 4, ks = bx & 15;
  const int q4 = lane >> 4, l16 = lane & 15;
  f16x8_t v;
  #pragma unroll
  for (int j = 0; j < 8; ++j)
    v[j] = (f16)Wp[(ks * 32 + q4 * 8 + j) * CD + cf * 16 + l16];
  *(f16x8_t*)(WpF + ((bx * 64) + lane) * 8) = v;
}

// ---------------- fused main: R19 CHAMPION restored verbatim (steady 411-419us).
// Structure: 64x64 wave tiles (R11), NT loads for H, NT scattered stores for Q,P,
// LDS swizzle mask (row&31)<<4 (bank conflicts 8.1e5), 4 barriers.
// Tested-null/negative around this point: store reorder (R13 445), LDS-coalesced
// stores (R12 486, R21 464), pipelined staging (R15 504), deferred Q (R16 579),
// 32x32 MFMA (R17 567), persistence +-NT (R14/R20 1275+).
// Register model: (512,4) -> 128 total regs/wave = 64 arch VGPR + 64 AGPR acc.
// SWIZZLE RULE (R4): XOR the FULL byte offset (XOR-last).
__global__ __launch_bounds__(NTHR, 4)
void fused_main(const float* __restrict__ Hl, const f16* __restrict__ MtF,
                const f16* __restrict__ WpF, const float* __restrict__ sb,
                float* __restrict__ outP, float* __restrict__ outQ) {
  __shared__ __align__(16) char AQraw[BM * HD * 2];   // 64 KiB: H fp16 -> Q fp16
  __shared__ float red[BM][8];
  __shared__ float rstat[BM];

  const int tid  = threadIdx.x;
  const int lane = tid & 63;
  const int wid  = tid >> 6;         // 0..7
  const int q4   = lane >> 4;        // 0..3
  const int l16  = lane & 15;
  const long rowbase = (long)blockIdx.x * BM;

  // ---- stage H: 64 rows x 512 fp32 -> fp16 LDS (swizzled); NT loads ----
  {
    const f32x4_t* __restrict__ src = (const f32x4_t*)(Hl + rowbase * HD);
    #pragma unroll
    for (int it = 0; it < (BM * HD / 4) / NTHR; ++it) {   // 16 iters
      const int f = it * NTHR + tid;
      const f32x4_t v = __builtin_nontemporal_load(&src[f]);
      const int row = f >> 7;
      int byteoff = row * (HD * 2) + ((f & 127) << 3);
      byteoff ^= (row & 31) << 4;                    // XOR-last!
      f16x4_t h;
      h[0] = (f16)v[0]; h[1] = (f16)v[1]; h[2] = (f16)v[2]; h[3] = (f16)v[3];
      *(f16x4_t*)(AQraw + byteoff) = h;
    }
  }
  __syncthreads();                                   // barrier 1

  // ---- GEMM1: wave tile 64 rows x 64 cols; B from MtF (L2) ----
  f32x4_t acc[4][4];
  #pragma unroll
  for (int i = 0; i < 4; ++i)
    #pragma unroll
    for (int j = 0; j < 4; ++j)
      #pragma unroll
      for (int k = 0; k < 4; ++k) acc[i][j][k] = 0.f;

  {
    const char* __restrict__ mb = (const char*)MtF + (wid * 4 * 16) * 1024 + lane * 16;
    for (int ks = 0; ks < 16; ++ks) {
      f16x8_t a[4];
      #pragma unroll
      for (int mf = 0; mf < 4; ++mf) {
        const int arow = mf * 16 + l16;
        int byteoff = arow * (HD * 2) + ks * 64 + q4 * 16;
        byteoff ^= (arow & 31) << 4;                 // XOR-last!
        a[mf] = *(const f16x8_t*)(AQraw + byteoff);
      }
      #pragma unroll
      for (int nf = 0; nf < 4; ++nf) {
        const f16x8_t b = *(const f16x8_t*)(mb + (nf * 16 + ks) * 1024);
        #pragma unroll
        for (int mf = 0; mf < 4; ++mf)
          acc[mf][nf] = __builtin_amdgcn_mfma_f32_16x16x32_f16(a[mf], b, acc[mf][nf], 0, 0, 0);
      }
    }
  }

  // ---- softmax over N=512, direct exp (|logit| <~ 54 << 88) ----
  // thread rows: mf*16 + q4*4 + r; cols: wid*64 + nf*16 + l16
  float sb10[4];
  #pragma unroll
  for (int nf = 0; nf < 4; ++nf) sb10[nf] = sb[wid * 64 + nf * 16 + l16] * TINV;

  float ps[4][4];
  #pragma unroll
  for (int mf = 0; mf < 4; ++mf)
    #pragma unroll
    for (int r = 0; r < 4; ++r) ps[mf][r] = 0.f;
  #pragma unroll
  for (int mf = 0; mf < 4; ++mf)
    #pragma unroll
    for (int nf = 0; nf < 4; ++nf)
      #pragma unroll
      for (int r = 0; r < 4; ++r) {
        const float e = __expf(fmaf(acc[mf][nf][r], TINV, sb10[nf]));
        acc[mf][nf][r] = e;
        ps[mf][r] += e;
      }
  #pragma unroll
  for (int st = 8; st >= 1; st >>= 1)
    #pragma unroll
    for (int mf = 0; mf < 4; ++mf)
      #pragma unroll
      for (int r = 0; r < 4; ++r)
        ps[mf][r] += __shfl_xor(ps[mf][r], st, 64);

  if (l16 == 0) {
    #pragma unroll
    for (int mf = 0; mf < 4; ++mf)
      #pragma unroll
      for (int r = 0; r < 4; ++r)
        red[mf * 16 + q4 * 4 + r][wid] = ps[mf][r];
  }
  __syncthreads();                                   // barrier 2
  if (tid < BM) {
    const float* rr = red[tid];
    rstat[tid] = 1.0f / (rr[0] + rr[1] + rr[2] + rr[3] + rr[4] + rr[5] + rr[6] + rr[7]);
  }
  __syncthreads();                                   // barrier 3

  // ---- normalize: Q fp32 NT stores + Q fp16 into LDS (transpose) ----
  #pragma unroll
  for (int mf = 0; mf < 4; ++mf) {
    float rinv[4];
    #pragma unroll
    for (int r = 0; r < 4; ++r)
      rinv[r] = rstat[mf * 16 + q4 * 4 + r];
    #pragma unroll
    for (int nf = 0; nf < 4; ++nf)
      #pragma unroll
      for (int r = 0; r < 4; ++r) {
        const int rloc = mf * 16 + q4 * 4 + r;
        const int col  = wid * 64 + nf * 16 + l16;
        const float q = acc[mf][nf][r] * rinv[r];
        __builtin_nontemporal_store(q, &outQ[(rowbase + rloc) * ND + col]);
        int byteoff = rloc * (ND * 2) + col * 2;
        byteoff ^= (rloc & 31) << 4;                 // XOR-last!
        *(f16*)(AQraw + byteoff) = (f16)q;
      }
  }
  __syncthreads();                                   // barrier 4: Q-LDS ready

  // ---- GEMM3: wave tile 64 rows x 32 cols; A from LDS, B from WpF (L2) ----
  f32x4_t acc2[4][2];
  #pragma unroll
  for (int i = 0; i < 4; ++i)
    #pragma unroll
    for (int j = 0; j < 2; ++j)
      #pragma unroll
      for (int k = 0; k < 4; ++k) acc2[i][j][k] = 0.f;

  {
    const char* __restrict__ wb = (const char*)WpF + (wid * 2 * 16) * 1024 + lane * 16;
    for (int ks = 0; ks < 16; ++ks) {
      f16x8_t a[4];
      #pragma unroll
      for (int mf = 0; mf < 4; ++mf) {
        const int arow = mf * 16 + l16;
        int byteoff = arow * (ND * 2) + ks * 64 + q4 * 16;
        byteoff ^= (arow & 31) << 4;                 // XOR-last!
        a[mf] = *(const f16x8_t*)(AQraw + byteoff);
      }
      #pragma unroll
      for (int nf = 0; nf < 2; ++nf) {
        const f16x8_t b = *(const f16x8_t*)(wb + (nf * 16 + ks) * 1024);
        #pragma unroll
        for (int mf = 0; mf < 4; ++mf)
          acc2[mf][nf] = __builtin_amdgcn_mfma_f32_16x16x32_f16(a[mf], b, acc2[mf][nf], 0, 0, 0);
      }
    }
  }

  // ---- P fp32 NT stores from regs ----
  #pragma unroll
  for (int mf = 0; mf < 4; ++mf)
    #pragma unroll
    for (int nf = 0; nf < 2; ++nf)
      #pragma unroll
      for (int r = 0; r < 4; ++r) {
        const long row = rowbase + mf * 16 + q4 * 4 + r;
        const int  col = wid * 32 + nf * 16 + l16;
        __builtin_nontemporal_store(acc2[mf][nf][r], &outP[row * CD + col]);
      }
}

extern "C" void kernel_launch(void* const* d_in, const int* in_sizes, int n_in,
                              void* d_out, int out_size, void* d_ws, size_t ws_size,
                              hipStream_t stream) {
  const float* Hl = (const float*)d_in[0];   // (B,T,V,H)
  const float* Wp = (const float*)d_in[1];   // (N,C)
  const float* Wq = (const float*)d_in[2];   // (C,H)
  const float* bq = (const float*)d_in[3];   // (C,)

  float* outP = (float*)d_out;                         // (M, C)
  float* outQ = (float*)d_out + (long)MROWS * CD;      // (M, N)

  f16*   MtF = (f16*)d_ws;                                        // 512 KiB
  f16*   WpF = (f16*)((char*)d_ws + ND * HD * 2);                 // 256 KiB
  float* sb  = (float*)((char*)d_ws + ND * HD * 2 + CD * ND * 2); // 2 KiB

  prep_M  <<<ND, CD, 0, stream>>>(Wp, Wq, bq, MtF, sb);
  prep_WpF<<<CD, 64, 0, stream>>>(Wp, WpF);
  fused_main<<<MROWS / BM, NTHR, 0, stream>>>(Hl, MtF, WpF, sb, outP, outQ);
}

// Round 23
// 402.226 us; speedup vs baseline: 3.1711x; 1.0660x over previous
//
#include <hip/hip_runtime.h>

typedef _Float16 f16;
typedef _Float16 f16x4_t __attribute__((ext_vector_type(4)));
typedef _Float16 f16x8_t __attribute__((ext_vector_type(8)));
typedef float    f32x4_t __attribute__((ext_vector_type(4)));

#define HD 512          // h
#define CD 256          // c
#define ND 512          // N (codebook)
#define MROWS (4*24*2048)
#define BM 48           // R23: 48 rows/WG -> LDS 51KB -> 3 WGs/CU (was 2)
#define NTHR 512
#define TINV 10.0f      // 1/TEMP

// Fragment layout for MFMA B operands (validated R6): element (n,h) ->
// ((((n>>4)*16+(h>>5))*4+((h>>3)&3))*16+(n&15))*8+(h&7)
__device__ __forceinline__ int fragoff(int n, int h) {
  return ((((n >> 4) * 16 + (h >> 5)) * 4 + ((h >> 3) & 3)) * 16 + (n & 15)) * 8 + (h & 7);
}

// ---------------- prep: M = Wp @ Wq -> fp16 fragments; sb[n] = dot(Wp[n], bq)
__global__ void prep_M(const float* __restrict__ Wp, const float* __restrict__ Wq,
                       const float* __restrict__ bq, f16* __restrict__ MtF,
                       float* __restrict__ sb) {
  const int n = blockIdx.x;   // 0..511
  const int t = threadIdx.x;  // 0..255
  __shared__ float wpr[CD];
  __shared__ float sred[CD];
  wpr[t] = Wp[n * CD + t];
  __syncthreads();
  float a0 = 0.f, a1 = 0.f;
  #pragma unroll 8
  for (int c = 0; c < CD; ++c) {
    const float w = wpr[c];
    a0 = fmaf(w, Wq[c * HD + t], a0);
    a1 = fmaf(w, Wq[c * HD + t + 256], a1);
  }
  MtF[fragoff(n, t)]       = (f16)a0;
  MtF[fragoff(n, t + 256)] = (f16)a1;
  sred[t] = wpr[t] * bq[t];
  __syncthreads();
  for (int s = 128; s > 0; s >>= 1) {
    if (t < s) sred[t] += sred[t + s];
    __syncthreads();
  }
  if (t == 0) sb[n] = sred[0];
}

// ---------------- prep: WpF = GEMM3 B fragments (k-dim = n, cols = c), validated R6
__global__ void prep_WpF(const float* __restrict__ Wp, f16* __restrict__ WpF) {
  const int bx   = blockIdx.x;        // cf*16 + ks, 0..255
  const int lane = threadIdx.x;       // 0..63
  const int cf = bx >> 4, ks = bx & 15;
  const int q4 = lane >> 4, l16 = lane & 15;
  f16x8_t v;
  #pragma unroll
  for (int j = 0; j < 8; ++j)
    v[j] = (f16)Wp[(ks * 32 + q4 * 8 + j) * CD + cf * 16 + l16];
  *(f16x8_t*)(WpF + ((bx * 64) + lane) * 8) = v;
}

// ---------------- fused main: R19/R22 champion body with BM 64->48 (ONLY change).
// LDS 68KB->51KB unlocks 3 WGs/CU (occupancy cap 42%->~63%) to anti-phase the
// HBM-idle GEMM/softmax windows. Wave tile: 48 rows x 64 cols (acc[3][4]);
// GEMM3 48x32 (acc2[3][2]). All per-wave col slices, fragment layouts, NT
// paths, swizzle, and 4 barriers identical to champion.
// Register model: (512,4) -> 128 total regs/wave; pool 2048/SIMD supports
// 6 waves x 128. SWIZZLE RULE (R4): XOR the FULL byte offset (XOR-last).
__global__ __launch_bounds__(NTHR, 4)
void fused_main(const float* __restrict__ Hl, const f16* __restrict__ MtF,
                const f16* __restrict__ WpF, const float* __restrict__ sb,
                float* __restrict__ outP, float* __restrict__ outQ) {
  __shared__ __align__(16) char AQraw[BM * HD * 2];   // 48 KiB: H fp16 -> Q fp16
  __shared__ float red[BM][8];
  __shared__ float rstat[BM];

  const int tid  = threadIdx.x;
  const int lane = tid & 63;
  const int wid  = tid >> 6;         // 0..7
  const int q4   = lane >> 4;        // 0..3
  const int l16  = lane & 15;
  const long rowbase = (long)blockIdx.x * BM;

  // ---- stage H: 48 rows x 512 fp32 -> fp16 LDS (swizzled); NT loads ----
  {
    const f32x4_t* __restrict__ src = (const f32x4_t*)(Hl + rowbase * HD);
    #pragma unroll
    for (int it = 0; it < (BM * HD / 4) / NTHR; ++it) {   // 12 iters
      const int f = it * NTHR + tid;
      const f32x4_t v = __builtin_nontemporal_load(&src[f]);
      const int row = f >> 7;
      int byteoff = row * (HD * 2) + ((f & 127) << 3);
      byteoff ^= (row & 31) << 4;                    // XOR-last!
      f16x4_t h;
      h[0] = (f16)v[0]; h[1] = (f16)v[1]; h[2] = (f16)v[2]; h[3] = (f16)v[3];
      *(f16x4_t*)(AQraw + byteoff) = h;
    }
  }
  __syncthreads();                                   // barrier 1

  // ---- GEMM1: wave tile 48 rows x 64 cols; B from MtF (L2) ----
  f32x4_t acc[3][4];
  #pragma unroll
  for (int i = 0; i < 3; ++i)
    #pragma unroll
    for (int j = 0; j < 4; ++j)
      #pragma unroll
      for (int k = 0; k < 4; ++k) acc[i][j][k] = 0.f;

  {
    const char* __restrict__ mb = (const char*)MtF + (wid * 4 * 16) * 1024 + lane * 16;
    for (int ks = 0; ks < 16; ++ks) {
      f16x8_t a[3];
      #pragma unroll
      for (int mf = 0; mf < 3; ++mf) {
        const int arow = mf * 16 + l16;
        int byteoff = arow * (HD * 2) + ks * 64 + q4 * 16;
        byteoff ^= (arow & 31) << 4;                 // XOR-last!
        a[mf] = *(const f16x8_t*)(AQraw + byteoff);
      }
      #pragma unroll
      for (int nf = 0; nf < 4; ++nf) {
        const f16x8_t b = *(const f16x8_t*)(mb + (nf * 16 + ks) * 1024);
        #pragma unroll
        for (int mf = 0; mf < 3; ++mf)
          acc[mf][nf] = __builtin_amdgcn_mfma_f32_16x16x32_f16(a[mf], b, acc[mf][nf], 0, 0, 0);
      }
    }
  }

  // ---- softmax over N=512, direct exp (|logit| <~ 54 << 88) ----
  // thread rows: mf*16 + q4*4 + r; cols: wid*64 + nf*16 + l16
  float sb10[4];
  #pragma unroll
  for (int nf = 0; nf < 4; ++nf) sb10[nf] = sb[wid * 64 + nf * 16 + l16] * TINV;

  float ps[3][4];
  #pragma unroll
  for (int mf = 0; mf < 3; ++mf)
    #pragma unroll
    for (int r = 0; r < 4; ++r) ps[mf][r] = 0.f;
  #pragma unroll
  for (int mf = 0; mf < 3; ++mf)
    #pragma unroll
    for (int nf = 0; nf < 4; ++nf)
      #pragma unroll
      for (int r = 0; r < 4; ++r) {
        const float e = __expf(fmaf(acc[mf][nf][r], TINV, sb10[nf]));
        acc[mf][nf][r] = e;
        ps[mf][r] += e;
      }
  #pragma unroll
  for (int st = 8; st >= 1; st >>= 1)
    #pragma unroll
    for (int mf = 0; mf < 3; ++mf)
      #pragma unroll
      for (int r = 0; r < 4; ++r)
        ps[mf][r] += __shfl_xor(ps[mf][r], st, 64);

  if (l16 == 0) {
    #pragma unroll
    for (int mf = 0; mf < 3; ++mf)
      #pragma unroll
      for (int r = 0; r < 4; ++r)
        red[mf * 16 + q4 * 4 + r][wid] = ps[mf][r];
  }
  __syncthreads();                                   // barrier 2
  if (tid < BM) {
    const float* rr = red[tid];
    rstat[tid] = 1.0f / (rr[0] + rr[1] + rr[2] + rr[3] + rr[4] + rr[5] + rr[6] + rr[7]);
  }
  __syncthreads();                                   // barrier 3

  // ---- normalize: Q fp32 NT stores + Q fp16 into LDS (transpose) ----
  #pragma unroll
  for (int mf = 0; mf < 3; ++mf) {
    float rinv[4];
    #pragma unroll
    for (int r = 0; r < 4; ++r)
      rinv[r] = rstat[mf * 16 + q4 * 4 + r];
    #pragma unroll
    for (int nf = 0; nf < 4; ++nf)
      #pragma unroll
      for (int r = 0; r < 4; ++r) {
        const int rloc = mf * 16 + q4 * 4 + r;
        const int col  = wid * 64 + nf * 16 + l16;
        const float q = acc[mf][nf][r] * rinv[r];
        __builtin_nontemporal_store(q, &outQ[(rowbase + rloc) * ND + col]);
        int byteoff = rloc * (ND * 2) + col * 2;
        byteoff ^= (rloc & 31) << 4;                 // XOR-last!
        *(f16*)(AQraw + byteoff) = (f16)q;
      }
  }
  __syncthreads();                                   // barrier 4: Q-LDS ready

  // ---- GEMM3: wave tile 48 rows x 32 cols; A from LDS, B from WpF (L2) ----
  f32x4_t acc2[3][2];
  #pragma unroll
  for (int i = 0; i < 3; ++i)
    #pragma unroll
    for (int j = 0; j < 2; ++j)
      #pragma unroll
      for (int k = 0; k < 4; ++k) acc2[i][j][k] = 0.f;

  {
    const char* __restrict__ wb = (const char*)WpF + (wid * 2 * 16) * 1024 + lane * 16;
    for (int ks = 0; ks < 16; ++ks) {
      f16x8_t a[3];
      #pragma unroll
      for (int mf = 0; mf < 3; ++mf) {
        const int arow = mf * 16 + l16;
        int byteoff = arow * (ND * 2) + ks * 64 + q4 * 16;
        byteoff ^= (arow & 31) << 4;                 // XOR-last!
        a[mf] = *(const f16x8_t*)(AQraw + byteoff);
      }
      #pragma unroll
      for (int nf = 0; nf < 2; ++nf) {
        const f16x8_t b = *(const f16x8_t*)(wb + (nf * 16 + ks) * 1024);
        #pragma unroll
        for (int mf = 0; mf < 3; ++mf)
          acc2[mf][nf] = __builtin_amdgcn_mfma_f32_16x16x32_f16(a[mf], b, acc2[mf][nf], 0, 0, 0);
      }
    }
  }

  // ---- P fp32 NT stores from regs ----
  #pragma unroll
  for (int mf = 0; mf < 3; ++mf)
    #pragma unroll
    for (int nf = 0; nf < 2; ++nf)
      #pragma unroll
      for (int r = 0; r < 4; ++r) {
        const long row = rowbase + mf * 16 + q4 * 4 + r;
        const int  col = wid * 32 + nf * 16 + l16;
        __builtin_nontemporal_store(acc2[mf][nf][r], &outP[row * CD + col]);
      }
}

extern "C" void kernel_launch(void* const* d_in, const int* in_sizes, int n_in,
                              void* d_out, int out_size, void* d_ws, size_t ws_size,
                              hipStream_t stream) {
  const float* Hl = (const float*)d_in[0];   // (B,T,V,H)
  const float* Wp = (const float*)d_in[1];   // (N,C)
  const float* Wq = (const float*)d_in[2];   // (C,H)
  const float* bq = (const float*)d_in[3];   // (C,)

  float* outP = (float*)d_out;                         // (M, C)
  float* outQ = (float*)d_out + (long)MROWS * CD;      // (M, N)

  f16*   MtF = (f16*)d_ws;                                        // 512 KiB
  f16*   WpF = (f16*)((char*)d_ws + ND * HD * 2);                 // 256 KiB
  float* sb  = (float*)((char*)d_ws + ND * HD * 2 + CD * ND * 2); // 2 KiB

  prep_M  <<<ND, CD, 0, stream>>>(Wp, Wq, bq, MtF, sb);
  prep_WpF<<<CD, 64, 0, stream>>>(Wp, WpF);
  fused_main<<<MROWS / BM, NTHR, 0, stream>>>(Hl, MtF, WpF, sb, outP, outQ);
}

// Round 24
// 332.041 us; speedup vs baseline: 3.8414x; 1.2114x over previous
//
#include <hip/hip_runtime.h>

typedef _Float16 f16;
typedef _Float16 f16x4_t __attribute__((ext_vector_type(4)));
typedef _Float16 f16x8_t __attribute__((ext_vector_type(8)));
typedef float    f32x4_t __attribute__((ext_vector_type(4)));

#define HD 512          // h
#define CD 256          // c
#define ND 512          // N (codebook)
#define MROWS (4*24*2048)
#define BM 32           // R24: 32 rows/WG -> LDS ~34KB -> 4 WGs/CU cap
#define NTHR 512
#define TINV 10.0f      // 1/TEMP

// Fragment layout for MFMA B operands (validated R6): element (n,h) ->
// ((((n>>4)*16+(h>>5))*4+((h>>3)&3))*16+(n&15))*8+(h&7)
__device__ __forceinline__ int fragoff(int n, int h) {
  return ((((n >> 4) * 16 + (h >> 5)) * 4 + ((h >> 3) & 3)) * 16 + (n & 15)) * 8 + (h & 7);
}

// ---------------- prep: M = Wp @ Wq -> fp16 fragments; sb[n] = dot(Wp[n], bq)
__global__ void prep_M(const float* __restrict__ Wp, const float* __restrict__ Wq,
                       const float* __restrict__ bq, f16* __restrict__ MtF,
                       float* __restrict__ sb) {
  const int n = blockIdx.x;   // 0..511
  const int t = threadIdx.x;  // 0..255
  __shared__ float wpr[CD];
  __shared__ float sred[CD];
  wpr[t] = Wp[n * CD + t];
  __syncthreads();
  float a0 = 0.f, a1 = 0.f;
  #pragma unroll 8
  for (int c = 0; c < CD; ++c) {
    const float w = wpr[c];
    a0 = fmaf(w, Wq[c * HD + t], a0);
    a1 = fmaf(w, Wq[c * HD + t + 256], a1);
  }
  MtF[fragoff(n, t)]       = (f16)a0;
  MtF[fragoff(n, t + 256)] = (f16)a1;
  sred[t] = wpr[t] * bq[t];
  __syncthreads();
  for (int s = 128; s > 0; s >>= 1) {
    if (t < s) sred[t] += sred[t + s];
    __syncthreads();
  }
  if (t == 0) sb[n] = sred[0];
}

// ---------------- prep: WpF = GEMM3 B fragments (k-dim = n, cols = c), validated R6
__global__ void prep_WpF(const float* __restrict__ Wp, f16* __restrict__ WpF) {
  const int bx   = blockIdx.x;        // cf*16 + ks, 0..255
  const int lane = threadIdx.x;       // 0..63
  const int cf = bx >> 4, ks = bx & 15;
  const int q4 = lane >> 4, l16 = lane & 15;
  f16x8_t v;
  #pragma unroll
  for (int j = 0; j < 8; ++j)
    v[j] = (f16)Wp[(ks * 32 + q4 * 8 + j) * CD + cf * 16 + l16];
  *(f16x8_t*)(WpF + ((bx * 64) + lane) * 8) = v;
}

// ---------------- fused main: R23 champion body with BM 48->32 (ONLY change).
// LDS 51KB->34KB -> 4 WGs/CU cap. Continuing the footprint/occupancy gradient
// that gave R22->R23 = 428->402 (FETCH dropped below H-size: L3 absorbing H).
// Wave tile: 32 rows x 64 cols (acc[2][4]); GEMM3 32x32 (acc2[2][2]).
// If this regresses, the curve bottomed at BM=48 -> restore R23, declare floor.
// Register model: (512,4) -> 128 total regs/wave. SWIZZLE RULE (R4): XOR the
// FULL byte offset (XOR-last); mask (row&31)<<4 (R17).
__global__ __launch_bounds__(NTHR, 4)
void fused_main(const float* __restrict__ Hl, const f16* __restrict__ MtF,
                const f16* __restrict__ WpF, const float* __restrict__ sb,
                float* __restrict__ outP, float* __restrict__ outQ) {
  __shared__ __align__(16) char AQraw[BM * HD * 2];   // 32 KiB: H fp16 -> Q fp16
  __shared__ float red[BM][8];
  __shared__ float rstat[BM];

  const int tid  = threadIdx.x;
  const int lane = tid & 63;
  const int wid  = tid >> 6;         // 0..7
  const int q4   = lane >> 4;        // 0..3
  const int l16  = lane & 15;
  const long rowbase = (long)blockIdx.x * BM;

  // ---- stage H: 32 rows x 512 fp32 -> fp16 LDS (swizzled); NT loads ----
  {
    const f32x4_t* __restrict__ src = (const f32x4_t*)(Hl + rowbase * HD);
    #pragma unroll
    for (int it = 0; it < (BM * HD / 4) / NTHR; ++it) {   // 8 iters
      const int f = it * NTHR + tid;
      const f32x4_t v = __builtin_nontemporal_load(&src[f]);
      const int row = f >> 7;
      int byteoff = row * (HD * 2) + ((f & 127) << 3);
      byteoff ^= (row & 31) << 4;                    // XOR-last!
      f16x4_t h;
      h[0] = (f16)v[0]; h[1] = (f16)v[1]; h[2] = (f16)v[2]; h[3] = (f16)v[3];
      *(f16x4_t*)(AQraw + byteoff) = h;
    }
  }
  __syncthreads();                                   // barrier 1

  // ---- GEMM1: wave tile 32 rows x 64 cols; B from MtF (L2) ----
  f32x4_t acc[2][4];
  #pragma unroll
  for (int i = 0; i < 2; ++i)
    #pragma unroll
    for (int j = 0; j < 4; ++j)
      #pragma unroll
      for (int k = 0; k < 4; ++k) acc[i][j][k] = 0.f;

  {
    const char* __restrict__ mb = (const char*)MtF + (wid * 4 * 16) * 1024 + lane * 16;
    for (int ks = 0; ks < 16; ++ks) {
      f16x8_t a[2];
      #pragma unroll
      for (int mf = 0; mf < 2; ++mf) {
        const int arow = mf * 16 + l16;
        int byteoff = arow * (HD * 2) + ks * 64 + q4 * 16;
        byteoff ^= (arow & 31) << 4;                 // XOR-last!
        a[mf] = *(const f16x8_t*)(AQraw + byteoff);
      }
      #pragma unroll
      for (int nf = 0; nf < 4; ++nf) {
        const f16x8_t b = *(const f16x8_t*)(mb + (nf * 16 + ks) * 1024);
        #pragma unroll
        for (int mf = 0; mf < 2; ++mf)
          acc[mf][nf] = __builtin_amdgcn_mfma_f32_16x16x32_f16(a[mf], b, acc[mf][nf], 0, 0, 0);
      }
    }
  }

  // ---- softmax over N=512, direct exp (|logit| <~ 54 << 88) ----
  // thread rows: mf*16 + q4*4 + r; cols: wid*64 + nf*16 + l16
  float sb10[4];
  #pragma unroll
  for (int nf = 0; nf < 4; ++nf) sb10[nf] = sb[wid * 64 + nf * 16 + l16] * TINV;

  float ps[2][4];
  #pragma unroll
  for (int mf = 0; mf < 2; ++mf)
    #pragma unroll
    for (int r = 0; r < 4; ++r) ps[mf][r] = 0.f;
  #pragma unroll
  for (int mf = 0; mf < 2; ++mf)
    #pragma unroll
    for (int nf = 0; nf < 4; ++nf)
      #pragma unroll
      for (int r = 0; r < 4; ++r) {
        const float e = __expf(fmaf(acc[mf][nf][r], TINV, sb10[nf]));
        acc[mf][nf][r] = e;
        ps[mf][r] += e;
      }
  #pragma unroll
  for (int st = 8; st >= 1; st >>= 1)
    #pragma unroll
    for (int mf = 0; mf < 2; ++mf)
      #pragma unroll
      for (int r = 0; r < 4; ++r)
        ps[mf][r] += __shfl_xor(ps[mf][r], st, 64);

  if (l16 == 0) {
    #pragma unroll
    for (int mf = 0; mf < 2; ++mf)
      #pragma unroll
      for (int r = 0; r < 4; ++r)
        red[mf * 16 + q4 * 4 + r][wid] = ps[mf][r];
  }
  __syncthreads();                                   // barrier 2
  if (tid < BM) {
    const float* rr = red[tid];
    rstat[tid] = 1.0f / (rr[0] + rr[1] + rr[2] + rr[3] + rr[4] + rr[5] + rr[6] + rr[7]);
  }
  __syncthreads();                                   // barrier 3

  // ---- normalize: Q fp32 NT stores + Q fp16 into LDS (transpose) ----
  #pragma unroll
  for (int mf = 0; mf < 2; ++mf) {
    float rinv[4];
    #pragma unroll
    for (int r = 0; r < 4; ++r)
      rinv[r] = rstat[mf * 16 + q4 * 4 + r];
    #pragma unroll
    for (int nf = 0; nf < 4; ++nf)
      #pragma unroll
      for (int r = 0; r < 4; ++r) {
        const int rloc = mf * 16 + q4 * 4 + r;
        const int col  = wid * 64 + nf * 16 + l16;
        const float q = acc[mf][nf][r] * rinv[r];
        __builtin_nontemporal_store(q, &outQ[(rowbase + rloc) * ND + col]);
        int byteoff = rloc * (ND * 2) + col * 2;
        byteoff ^= (rloc & 31) << 4;                 // XOR-last!
        *(f16*)(AQraw + byteoff) = (f16)q;
      }
  }
  __syncthreads();                                   // barrier 4: Q-LDS ready

  // ---- GEMM3: wave tile 32 rows x 32 cols; A from LDS, B from WpF (L2) ----
  f32x4_t acc2[2][2];
  #pragma unroll
  for (int i = 0; i < 2; ++i)
    #pragma unroll
    for (int j = 0; j < 2; ++j)
      #pragma unroll
      for (int k = 0; k < 4; ++k) acc2[i][j][k] = 0.f;

  {
    const char* __restrict__ wb = (const char*)WpF + (wid * 2 * 16) * 1024 + lane * 16;
    for (int ks = 0; ks < 16; ++ks) {
      f16x8_t a[2];
      #pragma unroll
      for (int mf = 0; mf < 2; ++mf) {
        const int arow = mf * 16 + l16;
        int byteoff = arow * (ND * 2) + ks * 64 + q4 * 16;
        byteoff ^= (arow & 31) << 4;                 // XOR-last!
        a[mf] = *(const f16x8_t*)(AQraw + byteoff);
      }
      #pragma unroll
      for (int nf = 0; nf < 2; ++nf) {
        const f16x8_t b = *(const f16x8_t*)(wb + (nf * 16 + ks) * 1024);
        #pragma unroll
        for (int mf = 0; mf < 2; ++mf)
          acc2[mf][nf] = __builtin_amdgcn_mfma_f32_16x16x32_f16(a[mf], b, acc2[mf][nf], 0, 0, 0);
      }
    }
  }

  // ---- P fp32 NT stores from regs ----
  #pragma unroll
  for (int mf = 0; mf < 2; ++mf)
    #pragma unroll
    for (int nf = 0; nf < 2; ++nf)
      #pragma unroll
      for (int r = 0; r < 4; ++r) {
        const long row = rowbase + mf * 16 + q4 * 4 + r;
        const int  col = wid * 32 + nf * 16 + l16;
        __builtin_nontemporal_store(acc2[mf][nf][r], &outP[row * CD + col]);
      }
}

extern "C" void kernel_launch(void* const* d_in, const int* in_sizes, int n_in,
                              void* d_out, int out_size, void* d_ws, size_t ws_size,
                              hipStream_t stream) {
  const float* Hl = (const float*)d_in[0];   // (B,T,V,H)
  const float* Wp = (const float*)d_in[1];   // (N,C)
  const float* Wq = (const float*)d_in[2];   // (C,H)
  const float* bq = (const float*)d_in[3];   // (C,)

  float* outP = (float*)d_out;                         // (M, C)
  float* outQ = (float*)d_out + (long)MROWS * CD;      // (M, N)

  f16*   MtF = (f16*)d_ws;                                        // 512 KiB
  f16*   WpF = (f16*)((char*)d_ws + ND * HD * 2);                 // 256 KiB
  float* sb  = (float*)((char*)d_ws + ND * HD * 2 + CD * ND * 2); // 2 KiB

  prep_M  <<<ND, CD, 0, stream>>>(Wp, Wq, bq, MtF, sb);
  prep_WpF<<<CD, 64, 0, stream>>>(Wp, WpF);
  fused_main<<<MROWS / BM, NTHR, 0, stream>>>(Hl, MtF, WpF, sb, outP, outQ);
}